// Round 9
// baseline (570.957 us; speedup 1.0000x reference)
//
#include <hip/hip_runtime.h>
#include <hip/hip_bf16.h>
#include <math.h>

// Problem constants
#define B_SZ 256
#define N_SZ 100000
#define E_SZ 1280
#define D_SZ 512

#define NCH2 782   // ceil(100000 / 128) j-chunks

typedef __attribute__((ext_vector_type(8))) short s8v;   // 8 bf16
typedef __attribute__((ext_vector_type(4))) float f32x4; // MFMA acc

__device__ __forceinline__ unsigned short f2bf(float f) {
  unsigned int u = __float_as_uint(f);
  u += 0x7fffu + ((u >> 16) & 1u);   // RNE
  return (unsigned short)(u >> 16);
}
// packs 2 f32 -> bf16x2 (RNE); compiler emits v_cvt_pk_bf16_f32
__device__ __forceinline__ unsigned int pack2(float a, float b) {
  union { __hip_bfloat162 h; unsigned u; } c;
  c.h = __float22bfloat162_rn(make_float2(a, b));
  return c.u;
}
// async global->LDS, 16B per lane; LDS dest = wave-uniform base + lane*16
__device__ __forceinline__ void gload16(const void* g, void* l) {
  __builtin_amdgcn_global_load_lds(
      (const __attribute__((address_space(1))) void*)g,
      (__attribute__((address_space(3))) void*)l, 16, 0, 0);
}

// top-8 streaming update; requires locals: bv[8], bi[8], minv, mins
#define TOP8_UPDATE(v_, i_)                                                 \
  if ((v_) > minv) {                                                        \
    _Pragma("unroll")                                                       \
    for (int s_ = 0; s_ < 8; ++s_)                                          \
      if (s_ == mins) { bv[s_] = (v_); bi[s_] = (i_); }                     \
    minv = bv[0]; mins = 0;                                                 \
    _Pragma("unroll")                                                       \
    for (int s_ = 1; s_ < 8; ++s_)                                          \
      if (bv[s_] < minv) { minv = bv[s_]; mins = s_; }                      \
  }

// ---------------- kernel 1: fused (normq | wt) prep ----------------
__global__ __launch_bounds__(256) void k_prep(const float* __restrict__ q,
                                              unsigned short* __restrict__ qn,
                                              const float* __restrict__ W,
                                              unsigned short* __restrict__ Wt) {
  __shared__ __align__(16) char sm[64 * 65 * 4];
  const int t = threadIdx.x;
  if (blockIdx.x < 256) {
    float* red = (float*)sm;
    int row = blockIdx.x;
    const float* src = q + (size_t)row * E_SZ;
    float x[5];
    float ss = 0.f;
#pragma unroll
    for (int i = 0; i < 5; ++i) { x[i] = src[t + 256 * i]; ss += x[i] * x[i]; }
#pragma unroll
    for (int o = 32; o > 0; o >>= 1) ss += __shfl_down(ss, o, 64);
    if ((t & 63) == 0) red[t >> 6] = ss;
    __syncthreads();
    float nrm = sqrtf(red[0] + red[1] + red[2] + red[3]);
    nrm = fmaxf(nrm, 1e-12f);
    float inv = 1.0f / nrm;
    unsigned short* dst = qn + (size_t)row * E_SZ;
#pragma unroll
    for (int i = 0; i < 5; ++i) dst[t + 256 * i] = f2bf(x[i] * inv);
  } else {
    float (*T)[65] = (float(*)[65])sm;
    int idx = blockIdx.x - 256;        // 0..159
    int kb = (idx % 20) * 64;
    int nb = (idx / 20) * 64;
#pragma unroll
    for (int i = 0; i < 16; ++i) {
      int kr = i * 4 + (t >> 6);
      T[kr][t & 63] = W[(size_t)(kb + kr) * D_SZ + nb + (t & 63)];
    }
    __syncthreads();
    const int n = t >> 2, ks = (t & 3) * 16;
    unsigned int ow[8];
#pragma unroll
    for (int j = 0; j < 8; ++j)
      ow[j] = (unsigned)f2bf(T[ks + 2 * j][n]) |
              ((unsigned)f2bf(T[ks + 2 * j + 1][n]) << 16);
    unsigned short* dst = Wt + (size_t)(nb + n) * E_SZ + kb + ks;
    *(uint4*)dst = make_uint4(ow[0], ow[1], ow[2], ow[3]);
    *(uint4*)(dst + 8) = make_uint4(ow[4], ow[5], ow[6], ow[7]);
  }
}

// ---------------- kernel 2: bf16 MFMA sims + fused per-chunk top-8 ----------
// 782 blocks x 512 thr (8 waves). Tile 256q x 128j, K=1280 in 40 steps of 32.
// Wave w: q-rows [64*(w>>1), +64), j-rows [64*(w&1), +64): acc[4][4] (64 AGPR).
// A (qn bf16): global_load_lds double-buffer, source-XOR swizzle, 2-way reads.
// B (emb f32): 2-set reg ring loaded 2 steps ahead -> cvt_pk -> LDS rows with
// 80B stride (2-way writes AND reads, no XOR). One raw barrier per step with
// counted s_waitcnt vmcnt(2): A-gloads (oldest) drained, next B loads fly on.
__global__ __launch_bounds__(512, 2) void k_sims_topk(
    const unsigned short* __restrict__ qn, const float* __restrict__ emb,
    const int* __restrict__ excl, float* __restrict__ cvalv,
    int* __restrict__ cvali) {
  __shared__ __align__(16) char lds[53248];
  // A0 @0 (16384), A1 @16384; B0 @32768 (10240), B1 @43008 (10240)
  const int t = threadIdx.x;
  const int l = t & 63, w = t >> 6;     // 8 waves
  const int r15 = l & 15, g = l >> 4;
  const int jbase = blockIdx.x * 128;

  f32x4 acc[4][4];
#pragma unroll
  for (int i = 0; i < 4; ++i)
#pragma unroll
    for (int j = 0; j < 4; ++j) acc[i][j] = (f32x4)0.f;

  // A fragment offsets (row*64B + XOR'd 16B chunk): 2-way conflict (free)
  const int fsw = ((g ^ (r15 & 3) ^ ((r15 >> 2) & 3)) << 4);
  int afoff[4];
#pragma unroll
  for (int mq = 0; mq < 4; ++mq)
    afoff[mq] = (64 * (w >> 1) + 16 * mq + r15) * 64 + fsw;
  // B fragment offsets (row*80B + g*16): 2-way conflict (free)
  int bfoff[4];
#pragma unroll
  for (int nj = 0; nj < 4; ++nj)
    bfoff[nj] = (64 * (w & 1) + 16 * nj + r15) * 80 + (g << 4);

  // A staging via gload_lds: 1024 chunks, 2 issues/thread; source XOR'd so
  // the linear LDS position p holds chunk (p&3)^swz(row).
  size_t aoffs0, aoffs1;
  int adst0, adst1;
  {
    int p0 = t, p1 = 512 + t;
    int row0 = p0 >> 2, row1 = p1 >> 2;
    int sw0 = (row0 & 3) ^ ((row0 >> 2) & 3);
    int sw1 = (row1 & 3) ^ ((row1 >> 2) & 3);
    aoffs0 = (size_t)row0 * E_SZ + (((p0 & 3) ^ sw0) * 8);
    aoffs1 = (size_t)row1 * E_SZ + (((p1 & 3) ^ sw1) * 8);
    adst0 = p0 * 16;
    adst1 = p1 * 16;
  }

  // B staging: thread t -> row t>>2 (0..127), 32B chunk t&3
  const int brow = t >> 2, bchunk = t & 3;
  const int bgrow = min(jbase + brow, N_SZ - 1);
  const float* bSrc = emb + (size_t)bgrow * E_SZ + bchunk * 8;
  const int bwoff = brow * 80 + bchunk * 16;

  float4 bs0[2], bs1[2];

#define STAGEA(kt_, dstoff_)                                                 \
  { gload16(qn + aoffs0 + (kt_), lds + (dstoff_) + adst0);                   \
    gload16(qn + aoffs1 + (kt_), lds + (dstoff_) + adst1); }
#define LOADB(set_, kt_)                                                     \
  { set_[0] = *(const float4*)(bSrc + (kt_));                                \
    set_[1] = *(const float4*)(bSrc + (kt_) + 4); }
#define CVTWR(set_, boff_)                                                   \
  { uint4 p_;                                                                \
    p_.x = pack2(set_[0].x, set_[0].y); p_.y = pack2(set_[0].z, set_[0].w);  \
    p_.z = pack2(set_[1].x, set_[1].y); p_.w = pack2(set_[1].z, set_[1].w);  \
    *(uint4*)(lds + (boff_) + bwoff) = p_; }
#define COMPUTE(aoff_, boff_)                                                \
  { s8v af_[4];                                                              \
    _Pragma("unroll") for (int mq_ = 0; mq_ < 4; ++mq_)                      \
      af_[mq_] = *(const s8v*)(lds + (aoff_) + afoff[mq_]);                  \
    _Pragma("unroll") for (int nj_ = 0; nj_ < 4; ++nj_) {                    \
      s8v bf_ = *(const s8v*)(lds + (boff_) + bfoff[nj_]);                   \
      _Pragma("unroll") for (int mq_ = 0; mq_ < 4; ++mq_)                    \
        acc[mq_][nj_] = __builtin_amdgcn_mfma_f32_16x16x32_bf16(             \
            af_[mq_], bf_, acc[mq_][nj_], 0, 0, 0);                          \
    } }

  // prologue: A(0)->Abuf0; B(0)->bs0, B(1)->bs1; write B(0)->Bbuf0
  STAGEA(0, 0);
  __builtin_amdgcn_sched_barrier(0);   // pin A-gloads oldest in vmcnt queue
  LOADB(bs0, 0);
  LOADB(bs1, 32);
  CVTWR(bs0, 32768);
  asm volatile("s_waitcnt vmcnt(2) lgkmcnt(0)" ::: "memory");
  __builtin_amdgcn_s_barrier();

  for (int s = 0; s < 40; s += 2) {
    // even step s (cur = buf0): stage A(s+1)->A1; load B(s+2)->bs0;
    // write B(s+1)(bs1)->B1; compute buf0.
    STAGEA((s + 1) * 32, 16384);
    __builtin_amdgcn_sched_barrier(0);
    if (s + 2 < 40) LOADB(bs0, (s + 2) * 32);
    CVTWR(bs1, 43008);
    COMPUTE(0, 32768);
    if (s + 2 < 40) {
      asm volatile("s_waitcnt vmcnt(2) lgkmcnt(0)" ::: "memory");
    } else {
      asm volatile("s_waitcnt vmcnt(0) lgkmcnt(0)" ::: "memory");
    }
    __builtin_amdgcn_s_barrier();
    // odd step s+1 (cur = buf1): stage A(s+2)->A0; load B(s+3)->bs1;
    // write B(s+2)(bs0)->B0; compute buf1.
    if (s + 2 < 40) {
      STAGEA((s + 2) * 32, 0);
      __builtin_amdgcn_sched_barrier(0);
    }
    if (s + 3 < 40) LOADB(bs1, (s + 3) * 32);
    if (s + 2 < 40) CVTWR(bs0, 32768);
    COMPUTE(16384, 43008);
    if (s + 3 < 40) {
      asm volatile("s_waitcnt vmcnt(2) lgkmcnt(0)" ::: "memory");
    } else if (s + 2 < 40) {
      asm volatile("s_waitcnt vmcnt(0) lgkmcnt(0)" ::: "memory");
    } else {
      asm volatile("s_waitcnt lgkmcnt(0)" ::: "memory");
    }
    __builtin_amdgcn_s_barrier();
  }
#undef STAGEA
#undef LOADB
#undef CVTWR
#undef COMPUTE

  // ---- top-8 scan: 4 phases of 64 q rows (waves {2p,2p+1} hold the data) --
  float* S = (float*)lds;                   // [64][132] f32 (33792 B)
  float* cV = (float*)(lds + 40960);        // [128][8]
  int*   cI = (int*)(lds + 45056);          // [128][8]
  for (int ph = 0; ph < 4; ++ph) {
    if ((w >> 1) == ph) {
      int jcol = 64 * (w & 1);
#pragma unroll
      for (int mq = 0; mq < 4; ++mq)
#pragma unroll
        for (int nj = 0; nj < 4; ++nj)
#pragma unroll
          for (int r = 0; r < 4; ++r)
            S[(16 * mq + 4 * g + r) * 132 + jcol + 16 * nj + r15] =
                acc[mq][nj][r];
    }
    __syncthreads();
    if (t < 128) {
      int qrow = t >> 1, half = t & 1;
      int q = ph * 64 + qrow;
      int ex = excl[q];
      float bv[8]; int bi[8];
#pragma unroll
      for (int s = 0; s < 8; ++s) { bv[s] = -1e30f; bi[s] = 0; }
      float minv = -1e30f; int mins = 0;
      const float* Srow = S + qrow * 132 + half * 64;
      int j0 = jbase + half * 64;
      for (int c = 0; c < 64; ++c) {
        int gj = j0 + c;
        float v = Srow[c];
        if (gj < N_SZ && gj != ex) { TOP8_UPDATE(v, gj); }
      }
#pragma unroll
      for (int s = 0; s < 8; ++s) { cV[t * 8 + s] = bv[s]; cI[t * 8 + s] = bi[s]; }
    }
    __syncthreads();
    if (t < 64) {
      int q = ph * 64 + t;
      float bv[8]; int bi[8];
#pragma unroll
      for (int s = 0; s < 8; ++s) { bv[s] = -1e30f; bi[s] = 0; }
      float minv = -1e30f; int mins = 0;
      for (int n = 0; n < 16; ++n) {
        float v = cV[t * 16 + n]; int ix = cI[t * 16 + n];
        TOP8_UPDATE(v, ix);
      }
      size_t base = ((size_t)q * NCH2 + blockIdx.x) * 8;
#pragma unroll
      for (int s = 0; s < 8; ++s) { cvalv[base + s] = bv[s]; cvali[base + s] = bi[s]; }
    }
    __syncthreads();
  }
}

// ---------------- kernel 3: merge per-chunk candidates -> global top-8 ------
__global__ __launch_bounds__(256) void k_merge(const float* __restrict__ cvalv,
                                               const int* __restrict__ cvali,
                                               int* __restrict__ topk) {
  __shared__ float sv[2048];
  __shared__ int si[2048];
  const int q = blockIdx.x, t = threadIdx.x;
  float bv[8]; int bi[8];
#pragma unroll
  for (int s = 0; s < 8; ++s) { bv[s] = -1e30f; bi[s] = 0; }
  float minv = -1e30f; int mins = 0;
  for (int c = t; c < NCH2; c += 256) {
    const float* vp = cvalv + ((size_t)q * NCH2 + c) * 8;
    const int* ip = cvali + ((size_t)q * NCH2 + c) * 8;
    float4 v0 = *(const float4*)vp, v1 = *(const float4*)(vp + 4);
    int4 i0 = *(const int4*)ip, i1 = *(const int4*)(ip + 4);
    float va[8] = {v0.x, v0.y, v0.z, v0.w, v1.x, v1.y, v1.z, v1.w};
    int ia[8] = {i0.x, i0.y, i0.z, i0.w, i1.x, i1.y, i1.z, i1.w};
#pragma unroll
    for (int s = 0; s < 8; ++s) {
      float v = va[s]; int ix = ia[s];
      TOP8_UPDATE(v, ix);
    }
  }
#pragma unroll
  for (int s = 0; s < 8; ++s) { sv[t * 8 + s] = bv[s]; si[t * 8 + s] = bi[s]; }
  __syncthreads();
  if (t < 64) {
    for (int rr = 1; rr < 4; ++rr) {
      int r = t + rr * 64;
#pragma unroll
      for (int s = 0; s < 8; ++s) {
        float v = sv[r * 8 + s]; int ix = si[r * 8 + s];
        TOP8_UPDATE(v, ix);
      }
    }
#pragma unroll
    for (int s = 0; s < 8; ++s) { sv[t * 8 + s] = bv[s]; si[t * 8 + s] = bi[s]; }
  }
  __syncthreads();
  if (t < 8) {
    for (int rr = 1; rr < 8; ++rr) {
      int r = t + rr * 8;
#pragma unroll
      for (int s = 0; s < 8; ++s) {
        float v = sv[r * 8 + s]; int ix = si[r * 8 + s];
        TOP8_UPDATE(v, ix);
      }
    }
#pragma unroll
    for (int s = 0; s < 8; ++s) { sv[t * 8 + s] = bv[s]; si[t * 8 + s] = bi[s]; }
  }
  __syncthreads();
  if (t == 0) {
    for (int r = 1; r < 8; ++r) {
#pragma unroll
      for (int s = 0; s < 8; ++s) {
        float v = sv[r * 8 + s]; int ix = si[r * 8 + s];
        TOP8_UPDATE(v, ix);
      }
    }
#pragma unroll
    for (int s = 0; s < 8; ++s) topk[q * 8 + s] = bi[s];
  }
}

// ---------------- kernel 4: gather + project via MFMA, bias fused -----------
// grid (16 Mtiles, 4 Ntiles), 256 thr (2x2 waves), tile 128x128, K=1280/64.
__global__ __launch_bounds__(256) void k_proj(
    const float* __restrict__ emb, const int* __restrict__ topk,
    const unsigned short* __restrict__ Wt, const float* __restrict__ bias,
    float* __restrict__ nproj) {
  __shared__ __align__(16) char lds[65536];  // A0 A1 B0 B1 each 16K
  const int t = threadIdx.x, l = t & 63, w = t >> 6;
  const int r15 = l & 15, g = l >> 4;
  const int wm = w >> 1, wn = w & 1;
  const int r0 = blockIdx.x * 128, n0 = blockIdx.y * 128;
  const int sr = t >> 3, kc = t & 7;

  int grow[4];
#pragma unroll
  for (int i = 0; i < 4; ++i) grow[i] = topk[r0 + i * 32 + sr];

  int woff[4];
#pragma unroll
  for (int i = 0; i < 4; ++i) {
    int row = i * 32 + sr;
    woff[i] = row * 128 + (((kc + (row & 7)) & 7) << 4);
  }
  int afoff[2][4], bfoff[2][4];
#pragma unroll
  for (int h = 0; h < 2; ++h) {
#pragma unroll
    for (int qq = 0; qq < 4; ++qq) {
      int rowa = 64 * wm + 16 * qq + r15;
      afoff[h][qq] = rowa * 128 + ((((h << 2) + g + (rowa & 7)) & 7) << 4);
      int rowb = 64 * wn + 16 * qq + r15;
      bfoff[h][qq] = rowb * 128 + ((((h << 2) + g + (rowb & 7)) & 7) << 4);
    }
  }

  f32x4 acc[4][4];
#pragma unroll
  for (int i = 0; i < 4; ++i)
#pragma unroll
    for (int j = 0; j < 4; ++j) acc[i][j] = (f32x4)0.f;

  float4 aset[4][2];
  s8v bset[4];

#define PLOADA(kt_)                                                          \
  { _Pragma("unroll") for (int i_ = 0; i_ < 4; ++i_) {                       \
      const float* s_ = emb + (size_t)grow[i_] * E_SZ + (kt_) + kc * 8;      \
      aset[i_][0] = *(const float4*)s_;                                      \
      aset[i_][1] = *(const float4*)(s_ + 4); } }
#define PLOADB(kt_)                                                          \
  { _Pragma("unroll") for (int i_ = 0; i_ < 4; ++i_)                         \
      bset[i_] = *(const s8v*)(Wt + (size_t)(n0 + i_ * 32 + sr) * E_SZ +     \
                               (kt_) + kc * 8); }
#define PWR(bA_, bB_)                                                        \
  { _Pragma("unroll") for (int i_ = 0; i_ < 4; ++i_) {                       \
      uint4 p_;                                                              \
      p_.x = pack2(aset[i_][0].x, aset[i_][0].y);                            \
      p_.y = pack2(aset[i_][0].z, aset[i_][0].w);                            \
      p_.z = pack2(aset[i_][1].x, aset[i_][1].y);                            \
      p_.w = pack2(aset[i_][1].z, aset[i_][1].w);                            \
      *(uint4*)((bA_) + woff[i_]) = p_;                                      \
      *(s8v*)((bB_) + woff[i_]) = bset[i_]; } }
#define PCOMP(bA_, bB_)                                                      \
  { _Pragma("unroll") for (int h_ = 0; h_ < 2; ++h_) {                       \
      s8v af_[4], bf_[4];                                                    \
      _Pragma("unroll") for (int q_ = 0; q_ < 4; ++q_) {                     \
        af_[q_] = *(const s8v*)((bA_) + afoff[h_][q_]);                      \
        bf_[q_] = *(const s8v*)((bB_) + bfoff[h_][q_]); }                    \
      _Pragma("unroll") for (int nj_ = 0; nj_ < 4; ++nj_)                    \
        _Pragma("unroll") for (int mq_ = 0; mq_ < 4; ++mq_)                  \
          acc[mq_][nj_] = __builtin_amdgcn_mfma_f32_16x16x32_bf16(           \
              af_[mq_], bf_[nj_], acc[mq_][nj_], 0, 0, 0); } }

  PLOADA(0); PLOADB(0);
  PWR(lds, lds + 32768);
  __syncthreads();
  for (int s = 0; s < 20; ++s) {
    char* cA = lds + (s & 1) * 16384;
    char* cB = lds + 32768 + (s & 1) * 16384;
    char* nA = lds + ((s + 1) & 1) * 16384;
    char* nB = lds + 32768 + ((s + 1) & 1) * 16384;
    if (s + 1 < 20) { PLOADA((s + 1) * 64); PLOADB((s + 1) * 64); }
    PCOMP(cA, cB);
    if (s + 1 < 20) { PWR(nA, nB); }
    __syncthreads();
  }
#pragma unroll
  for (int nj = 0; nj < 4; ++nj) {
    int n = n0 + 64 * wn + 16 * nj + r15;
    float bn = bias[n];
#pragma unroll
    for (int mq = 0; mq < 4; ++mq) {
      int m = r0 + 64 * wm + 16 * mq + 4 * g;
#pragma unroll
      for (int r = 0; r < 4; ++r)
        nproj[(size_t)(m + r) * D_SZ + n] = acc[mq][nj][r] + bn;
    }
  }
#undef PLOADA
#undef PLOADB
#undef PWR
#undef PCOMP
}

// ---------------- kernel 5: attention + logits + per-query loss partial -----
__global__ __launch_bounds__(256) void k_attn(
    const float* __restrict__ model, const float* __restrict__ proj,
    const int* __restrict__ topk, const int* __restrict__ labels,
    const float* __restrict__ clfW, const float* __restrict__ clfb,
    float* __restrict__ out, float* __restrict__ lossp) {
  __shared__ float P[8 * 512];
  __shared__ float red[4];
  int b = blockIdx.x, t = threadIdx.x;
  const float* src = proj + (size_t)b * 8 * 512;
#pragma unroll
  for (int i = 0; i < 4; ++i) {
    int o = i * 1024 + t * 4;
    *(float4*)&P[o] = *(const float4*)&src[o];
  }
  __syncthreads();
  float m0 = model[b * 512 + t], m1 = model[b * 512 + 256 + t];

  float sc[8];
#pragma unroll
  for (int k = 0; k < 8; ++k) {
    float p = m0 * P[k * 512 + t] + m1 * P[k * 512 + 256 + t];
#pragma unroll
    for (int o = 32; o > 0; o >>= 1) p += __shfl_down(p, o, 64);
    if ((t & 63) == 0) red[t >> 6] = p;
    __syncthreads();
    sc[k] = red[0] + red[1] + red[2] + red[3];
    __syncthreads();
  }
  const float scale = 0.04419417382415922f;  // 1/sqrt(512)
  float mx = -1e30f;
  float s_[8];
#pragma unroll
  for (int k = 0; k < 8; ++k) { s_[k] = sc[k] * scale; mx = fmaxf(mx, s_[k]); }
  float den = 0.f, att[8];
#pragma unroll
  for (int k = 0; k < 8; ++k) { att[k] = expf(s_[k] - mx); den += att[k]; }
  float iden = 1.0f / den;
#pragma unroll
  for (int k = 0; k < 8; ++k) att[k] *= iden;

  float z0 = 0.f, z1 = 0.f;
#pragma unroll
  for (int k = 0; k < 8; ++k) {
    z0 = fmaf(att[k], P[k * 512 + t], z0);
    z1 = fmaf(att[k], P[k * 512 + 256 + t], z1);
  }
#pragma unroll
  for (int c = 0; c < 2; ++c) {
    float lp = m0 * clfW[t * 2 + c] + m1 * clfW[(t + 256) * 2 + c] +
               z0 * clfW[(512 + t) * 2 + c] + z1 * clfW[(768 + t) * 2 + c];
#pragma unroll
    for (int o = 32; o > 0; o >>= 1) lp += __shfl_down(lp, o, 64);
    if ((t & 63) == 0) red[t >> 6] = lp;
    __syncthreads();
    if (t == 0) out[b * 2 + c] = red[0] + red[1] + red[2] + red[3] + clfb[c];
    __syncthreads();
  }
  float cp = 0.f, cn = 0.f;
  float p0 = 0.f, p1 = 0.f, n0 = 0.f, n1 = 0.f;
#pragma unroll
  for (int k = 0; k < 8; ++k) {
    int lb = labels[topk[b * 8 + k]];
    float mp = (lb == 1) ? 1.f : 0.f;
    float mn = (lb == 0) ? 1.f : 0.f;
    cp += mp; cn += mn;
    p0 = fmaf(mp, P[k * 512 + t], p0);
    p1 = fmaf(mp, P[k * 512 + 256 + t], p1);
    n0 = fmaf(mn, P[k * 512 + t], n0);
    n1 = fmaf(mn, P[k * 512 + 256 + t], n1);
  }
  float icp = 1.0f / (cp + 1e-6f), icn = 1.0f / (cn + 1e-6f);
  p0 *= icp; p1 *= icp; n0 *= icn; n1 *= icn;
  float lq = (m0 - p0) * (m0 - p0) + (m1 - p1) * (m1 - p1) -
             0.5f * ((m0 - n0) * (m0 - n0) + (m1 - n1) * (m1 - n1));
#pragma unroll
  for (int o = 32; o > 0; o >>= 1) lq += __shfl_down(lq, o, 64);
  if ((t & 63) == 0) red[t >> 6] = lq;
  __syncthreads();
  if (t == 0) lossp[b] = red[0] + red[1] + red[2] + red[3];
}

// ---------------- kernel 6: final loss reduction ----------------
__global__ __launch_bounds__(256) void k_loss(const float* __restrict__ lossp,
                                              float* __restrict__ out) {
  __shared__ float red[4];
  int t = threadIdx.x;
  float v = lossp[t];
#pragma unroll
  for (int o = 32; o > 0; o >>= 1) v += __shfl_down(v, o, 64);
  if ((t & 63) == 0) red[t >> 6] = v;
  __syncthreads();
  if (t == 0)
    out[512] = (red[0] + red[1] + red[2] + red[3]) * (1.0f / (256.0f * 512.0f));
}

extern "C" void kernel_launch(void* const* d_in, const int* in_sizes, int n_in,
                              void* d_out, int out_size, void* d_ws,
                              size_t ws_size, hipStream_t stream) {
  (void)in_sizes; (void)n_in; (void)out_size; (void)ws_size;
  const float* q      = (const float*)d_in[0];  // [256,1280]
  const float* model  = (const float*)d_in[1];  // [256,512]
  const float* emb    = (const float*)d_in[2];  // [100000,1280]
  const int*   labels = (const int*)d_in[3];    // [100000]
  const int*   excl   = (const int*)d_in[4];    // [256]
  const float* projW  = (const float*)d_in[5];  // [1280,512]
  const float* projb  = (const float*)d_in[6];  // [512]
  const float* clfW   = (const float*)d_in[7];  // [1024,2]
  const float* clfb   = (const float*)d_in[8];  // [2]
  float* out = (float*)d_out;                   // 512 logits + 1 loss

  // workspace layout (bytes)
  char* ws = (char*)d_ws;
  unsigned short* qn = (unsigned short*)ws;               // 655,360
  unsigned short* Wt = (unsigned short*)(ws + 655360);    // 1,310,720
  float* cvalv = (float*)(ws + 1966080);                  // 782*256*8*4 = 6,406,144
  int*   cvali = (int*)(ws + 8372224);                    // 6,406,144
  int*   topk  = (int*)(ws + 14778368);                   // 8,192
  float* nproj = (float*)(ws + 14786560);                 // 4,194,304
  float* lossp = (float*)(ws + 18980864);                 // 1,024

  k_prep<<<416, 256, 0, stream>>>(q, qn, projW, Wt);
  k_sims_topk<<<NCH2, 512, 0, stream>>>(qn, emb, excl, cvalv, cvali);
  k_merge<<<256, 256, 0, stream>>>(cvalv, cvali, topk);
  k_proj<<<dim3(16, 4), 256, 0, stream>>>(emb, topk, Wt, projb, nproj);
  k_attn<<<256, 256, 0, stream>>>(model, nproj, topk, labels, clfW, clfb, out, lossp);
  k_loss<<<1, 256, 0, stream>>>(lossp, out);
}

// Round 10
// 501.667 us; speedup vs baseline: 1.1381x; 1.1381x over previous
//
#include <hip/hip_runtime.h>
#include <hip/hip_bf16.h>
#include <math.h>

// Problem constants
#define B_SZ 256
#define N_SZ 100000
#define E_SZ 1280
#define D_SZ 512

#define NCHJ 782   // ceil(100000 / 128) j-chunks

typedef __attribute__((ext_vector_type(8))) short s8v;   // 8 bf16
typedef __attribute__((ext_vector_type(4))) float f32x4; // MFMA acc

__device__ __forceinline__ unsigned short f2bf(float f) {
  unsigned int u = __float_as_uint(f);
  u += 0x7fffu + ((u >> 16) & 1u);   // RNE
  return (unsigned short)(u >> 16);
}
// packs 2 f32 -> bf16x2 (RNE); compiler emits v_cvt_pk_bf16_f32
__device__ __forceinline__ unsigned int pack2(float a, float b) {
  union { __hip_bfloat162 h; unsigned u; } c;
  c.h = __float22bfloat162_rn(make_float2(a, b));
  return c.u;
}
// async global->LDS, 16B per lane; LDS dest = wave-uniform base + lane*16
__device__ __forceinline__ void gload16(const void* g, void* l) {
  __builtin_amdgcn_global_load_lds(
      (const __attribute__((address_space(1))) void*)g,
      (__attribute__((address_space(3))) void*)l, 16, 0, 0);
}

// top-8 streaming update; requires locals: bv[8], bi[8], minv, mins
#define TOP8_UPDATE(v_, i_)                                                 \
  if ((v_) > minv) {                                                        \
    _Pragma("unroll")                                                       \
    for (int s_ = 0; s_ < 8; ++s_)                                          \
      if (s_ == mins) { bv[s_] = (v_); bi[s_] = (i_); }                     \
    minv = bv[0]; mins = 0;                                                 \
    _Pragma("unroll")                                                       \
    for (int s_ = 1; s_ < 8; ++s_)                                          \
      if (bv[s_] < minv) { minv = bv[s_]; mins = s_; }                      \
  }

// ---------------- kernel 0: stream-convert emb f32 -> bf16 ----------------
// 128M f32 -> 128M bf16. Per iter: 32B contiguous in / 16B contiguous out.
__global__ __launch_bounds__(256) void k_conv(const float* __restrict__ in,
                                              unsigned short* __restrict__ outp) {
  const size_t T = (size_t)gridDim.x * 256;
  const size_t total = 16000000u;  // (100000*1280)/8
  for (size_t i = (size_t)blockIdx.x * 256 + threadIdx.x; i < total; i += T) {
    const float4* p = ((const float4*)in) + 2 * i;
    float4 a = p[0], b = p[1];
    uint4 o;
    o.x = pack2(a.x, a.y); o.y = pack2(a.z, a.w);
    o.z = pack2(b.x, b.y); o.w = pack2(b.z, b.w);
    ((uint4*)outp)[i] = o;
  }
}

// ---------------- kernel 1: fused (normq | wt) prep ----------------
__global__ __launch_bounds__(256) void k_prep(const float* __restrict__ q,
                                              unsigned short* __restrict__ qn,
                                              const float* __restrict__ W,
                                              unsigned short* __restrict__ Wt) {
  __shared__ __align__(16) char sm[64 * 65 * 4];
  const int t = threadIdx.x;
  if (blockIdx.x < 256) {
    float* red = (float*)sm;
    int row = blockIdx.x;
    const float* src = q + (size_t)row * E_SZ;
    float x[5];
    float ss = 0.f;
#pragma unroll
    for (int i = 0; i < 5; ++i) { x[i] = src[t + 256 * i]; ss += x[i] * x[i]; }
#pragma unroll
    for (int o = 32; o > 0; o >>= 1) ss += __shfl_down(ss, o, 64);
    if ((t & 63) == 0) red[t >> 6] = ss;
    __syncthreads();
    float nrm = sqrtf(red[0] + red[1] + red[2] + red[3]);
    nrm = fmaxf(nrm, 1e-12f);
    float inv = 1.0f / nrm;
    unsigned short* dst = qn + (size_t)row * E_SZ;
#pragma unroll
    for (int i = 0; i < 5; ++i) dst[t + 256 * i] = f2bf(x[i] * inv);
  } else {
    float (*T)[65] = (float(*)[65])sm;
    int idx = blockIdx.x - 256;        // 0..159
    int kb = (idx % 20) * 64;
    int nb = (idx / 20) * 64;
#pragma unroll
    for (int i = 0; i < 16; ++i) {
      int kr = i * 4 + (t >> 6);
      T[kr][t & 63] = W[(size_t)(kb + kr) * D_SZ + nb + (t & 63)];
    }
    __syncthreads();
    const int n = t >> 2, ks = (t & 3) * 16;
    unsigned int ow[8];
#pragma unroll
    for (int j = 0; j < 8; ++j)
      ow[j] = (unsigned)f2bf(T[ks + 2 * j][n]) |
              ((unsigned)f2bf(T[ks + 2 * j + 1][n]) << 16);
    unsigned short* dst = Wt + (size_t)(nb + n) * E_SZ + kb + ks;
    *(uint4*)dst = make_uint4(ow[0], ow[1], ow[2], ow[3]);
    *(uint4*)(dst + 8) = make_uint4(ow[4], ow[5], ow[6], ow[7]);
  }
}

// ---------------- kernel 2: bf16 MFMA sims + fused per-chunk top-8 ----------
// m97-replica structure: 1564 blocks (782 j-tiles x 2 m-tiles) x 256 thr
// (4 waves, 2x2). Tile 128q x 128j, BK=32, K=1280 in 40 steps. Both operands
// staged via global_load_lds width-16 into LINEAR LDS (A @0, B @8192, 8KB
// each, single-buffered); two __syncthreads per step (compiler emits drains);
// ds_read_b128 fragment reads; acc[4][4] per wave. Top-8 scan epilogue
// overlays the staging LDS after the K-loop.
__global__ __launch_bounds__(256) void k_sims_topk(
    const unsigned short* __restrict__ qn, const unsigned short* __restrict__ ebf,
    const int* __restrict__ excl, float* __restrict__ cvalv,
    int* __restrict__ cvali) {
  __shared__ __align__(16) char lds[41984];
  // K-loop: A [128][64B] @0, B [128][64B] @8192. Scan: S f32[64][132] @0,
  // cV @33792 (4KB), cI @37888 (4KB).
  const int t = threadIdx.x;
  const int l = t & 63, w = t >> 6;
  const int r15 = l & 15, g = l >> 4;
  const int wm = w >> 1, wn = w & 1;
  const int jt = blockIdx.x >> 1, mt = blockIdx.x & 1;
  const int jbase = jt * 128, qbase = mt * 128;

  f32x4 acc[4][4];
#pragma unroll
  for (int i = 0; i < 4; ++i)
#pragma unroll
    for (int j = 0; j < 4; ++j) acc[i][j] = (f32x4)0.f;

  // staging: 512 chunks of 16B per tile; thread t handles chunks t and t+256
  const int srow = t >> 2, scol = (t & 3) * 8;
  const unsigned short* aS0 = qn + (size_t)(qbase + srow) * E_SZ + scol;
  const unsigned short* aS1 = qn + (size_t)(qbase + 64 + srow) * E_SZ + scol;
  const int jr0 = min(jbase + srow, N_SZ - 1);
  const int jr1 = min(jbase + 64 + srow, N_SZ - 1);
  const unsigned short* bS0 = ebf + (size_t)jr0 * E_SZ + scol;
  const unsigned short* bS1 = ebf + (size_t)jr1 * E_SZ + scol;
  const int d0 = t * 16, d1 = 4096 + t * 16;

  int afoff[4], bfoff[4];
#pragma unroll
  for (int mq = 0; mq < 4; ++mq)
    afoff[mq] = (64 * wm + 16 * mq + r15) * 64 + g * 16;
#pragma unroll
  for (int nj = 0; nj < 4; ++nj)
    bfoff[nj] = 8192 + (64 * wn + 16 * nj + r15) * 64 + g * 16;

  for (int kt = 0; kt < E_SZ; kt += 32) {
    gload16(aS0 + kt, lds + d0);
    gload16(aS1 + kt, lds + d1);
    gload16(bS0 + kt, lds + 8192 + d0);
    gload16(bS1 + kt, lds + 8192 + d1);
    __syncthreads();
    s8v af[4], bf[4];
#pragma unroll
    for (int mq = 0; mq < 4; ++mq) af[mq] = *(const s8v*)(lds + afoff[mq]);
#pragma unroll
    for (int nj = 0; nj < 4; ++nj) bf[nj] = *(const s8v*)(lds + bfoff[nj]);
#pragma unroll
    for (int nj = 0; nj < 4; ++nj)
#pragma unroll
      for (int mq = 0; mq < 4; ++mq)
        acc[mq][nj] = __builtin_amdgcn_mfma_f32_16x16x32_bf16(
            af[mq], bf[nj], acc[mq][nj], 0, 0, 0);
    __syncthreads();
  }

  // ---- top-8 scan epilogue: 2 phases over q-halves (wm) ----
  float* S = (float*)lds;              // [64][132]
  float* cV = (float*)(lds + 33792);   // [128][8]
  int*   cI = (int*)(lds + 37888);     // [128][8]
  for (int ph = 0; ph < 2; ++ph) {
    __syncthreads();
    if (wm == ph) {
#pragma unroll
      for (int mq = 0; mq < 4; ++mq)
#pragma unroll
        for (int nj = 0; nj < 4; ++nj)
#pragma unroll
          for (int r = 0; r < 4; ++r)
            S[(16 * mq + 4 * g + r) * 132 + 64 * wn + 16 * nj + r15] =
                acc[mq][nj][r];
    }
    __syncthreads();
    if (t < 128) {
      int qrow = t >> 1, half = t & 1;
      int q = qbase + ph * 64 + qrow;
      int ex = excl[q];
      float bv[8]; int bi[8];
#pragma unroll
      for (int s = 0; s < 8; ++s) { bv[s] = -1e30f; bi[s] = 0; }
      float minv = -1e30f; int mins = 0;
      const float* Sr = S + qrow * 132 + half * 64;
      int jb = jbase + half * 64;
      for (int c = 0; c < 64; ++c) {
        int gj = jb + c;
        float v = Sr[c];
        if (gj < N_SZ && gj != ex) { TOP8_UPDATE(v, gj); }
      }
#pragma unroll
      for (int s = 0; s < 8; ++s) {
        cV[(qrow * 2 + half) * 8 + s] = bv[s];
        cI[(qrow * 2 + half) * 8 + s] = bi[s];
      }
    }
    __syncthreads();
    if (t < 64) {
      int q = qbase + ph * 64 + t;
      float bv[8]; int bi[8];
#pragma unroll
      for (int s = 0; s < 8; ++s) { bv[s] = -1e30f; bi[s] = 0; }
      float minv = -1e30f; int mins = 0;
      for (int n = 0; n < 16; ++n) {
        float v = cV[t * 16 + n]; int ix = cI[t * 16 + n];
        TOP8_UPDATE(v, ix);
      }
      size_t base = ((size_t)q * NCHJ + jt) * 8;
#pragma unroll
      for (int s = 0; s < 8; ++s) { cvalv[base + s] = bv[s]; cvali[base + s] = bi[s]; }
    }
  }
}

// ---------------- kernel 3: merge per-chunk candidates -> global top-8 ------
__global__ __launch_bounds__(256) void k_merge(const float* __restrict__ cvalv,
                                               const int* __restrict__ cvali,
                                               int* __restrict__ topk) {
  __shared__ float sv[2048];
  __shared__ int si[2048];
  const int q = blockIdx.x, t = threadIdx.x;
  float bv[8]; int bi[8];
#pragma unroll
  for (int s = 0; s < 8; ++s) { bv[s] = -1e30f; bi[s] = 0; }
  float minv = -1e30f; int mins = 0;
  for (int c = t; c < NCHJ; c += 256) {
    const float* vp = cvalv + ((size_t)q * NCHJ + c) * 8;
    const int* ip = cvali + ((size_t)q * NCHJ + c) * 8;
    float4 v0 = *(const float4*)vp, v1 = *(const float4*)(vp + 4);
    int4 i0 = *(const int4*)ip, i1 = *(const int4*)(ip + 4);
    float va[8] = {v0.x, v0.y, v0.z, v0.w, v1.x, v1.y, v1.z, v1.w};
    int ia[8] = {i0.x, i0.y, i0.z, i0.w, i1.x, i1.y, i1.z, i1.w};
#pragma unroll
    for (int s = 0; s < 8; ++s) {
      float v = va[s]; int ix = ia[s];
      TOP8_UPDATE(v, ix);
    }
  }
#pragma unroll
  for (int s = 0; s < 8; ++s) { sv[t * 8 + s] = bv[s]; si[t * 8 + s] = bi[s]; }
  __syncthreads();
  if (t < 64) {
    for (int rr = 1; rr < 4; ++rr) {
      int r = t + rr * 64;
#pragma unroll
      for (int s = 0; s < 8; ++s) {
        float v = sv[r * 8 + s]; int ix = si[r * 8 + s];
        TOP8_UPDATE(v, ix);
      }
    }
#pragma unroll
    for (int s = 0; s < 8; ++s) { sv[t * 8 + s] = bv[s]; si[t * 8 + s] = bi[s]; }
  }
  __syncthreads();
  if (t < 8) {
    for (int rr = 1; rr < 8; ++rr) {
      int r = t + rr * 8;
#pragma unroll
      for (int s = 0; s < 8; ++s) {
        float v = sv[r * 8 + s]; int ix = si[r * 8 + s];
        TOP8_UPDATE(v, ix);
      }
    }
#pragma unroll
    for (int s = 0; s < 8; ++s) { sv[t * 8 + s] = bv[s]; si[t * 8 + s] = bi[s]; }
  }
  __syncthreads();
  if (t == 0) {
    for (int r = 1; r < 8; ++r) {
#pragma unroll
      for (int s = 0; s < 8; ++s) {
        float v = sv[r * 8 + s]; int ix = si[r * 8 + s];
        TOP8_UPDATE(v, ix);
      }
    }
#pragma unroll
    for (int s = 0; s < 8; ++s) topk[q * 8 + s] = bi[s];
  }
}

// ---------------- kernel 4: gather + project via MFMA, bias fused -----------
// grid (16 Mtiles, 4 Ntiles), 256 thr (2x2 waves), tile 128x128, K=1280/64.
__global__ __launch_bounds__(256) void k_proj(
    const float* __restrict__ emb, const int* __restrict__ topk,
    const unsigned short* __restrict__ Wt, const float* __restrict__ bias,
    float* __restrict__ nproj) {
  __shared__ __align__(16) char lds[65536];  // A0 A1 B0 B1 each 16K
  const int t = threadIdx.x, l = t & 63, w = t >> 6;
  const int r15 = l & 15, g = l >> 4;
  const int wm = w >> 1, wn = w & 1;
  const int r0 = blockIdx.x * 128, n0 = blockIdx.y * 128;
  const int sr = t >> 3, kc = t & 7;

  int grow[4];
#pragma unroll
  for (int i = 0; i < 4; ++i) grow[i] = topk[r0 + i * 32 + sr];

  int woff[4];
#pragma unroll
  for (int i = 0; i < 4; ++i) {
    int row = i * 32 + sr;
    woff[i] = row * 128 + (((kc + (row & 7)) & 7) << 4);
  }
  int afoff[2][4], bfoff[2][4];
#pragma unroll
  for (int h = 0; h < 2; ++h) {
#pragma unroll
    for (int qq = 0; qq < 4; ++qq) {
      int rowa = 64 * wm + 16 * qq + r15;
      afoff[h][qq] = rowa * 128 + ((((h << 2) + g + (rowa & 7)) & 7) << 4);
      int rowb = 64 * wn + 16 * qq + r15;
      bfoff[h][qq] = rowb * 128 + ((((h << 2) + g + (rowb & 7)) & 7) << 4);
    }
  }

  f32x4 acc[4][4];
#pragma unroll
  for (int i = 0; i < 4; ++i)
#pragma unroll
    for (int j = 0; j < 4; ++j) acc[i][j] = (f32x4)0.f;

  float4 aset[4][2];
  s8v bset[4];

#define PLOADA(kt_)                                                          \
  { _Pragma("unroll") for (int i_ = 0; i_ < 4; ++i_) {                       \
      const float* s_ = emb + (size_t)grow[i_] * E_SZ + (kt_) + kc * 8;      \
      aset[i_][0] = *(const float4*)s_;                                      \
      aset[i_][1] = *(const float4*)(s_ + 4); } }
#define PLOADB(kt_)                                                          \
  { _Pragma("unroll") for (int i_ = 0; i_ < 4; ++i_)                         \
      bset[i_] = *(const s8v*)(Wt + (size_t)(n0 + i_ * 32 + sr) * E_SZ +     \
                               (kt_) + kc * 8); }
#define PWR(bA_, bB_)                                                        \
  { _Pragma("unroll") for (int i_ = 0; i_ < 4; ++i_) {                       \
      uint4 p_;                                                              \
      p_.x = pack2(aset[i_][0].x, aset[i_][0].y);                            \
      p_.y = pack2(aset[i_][0].z, aset[i_][0].w);                            \
      p_.z = pack2(aset[i_][1].x, aset[i_][1].y);                            \
      p_.w = pack2(aset[i_][1].z, aset[i_][1].w);                            \
      *(uint4*)((bA_) + woff[i_]) = p_;                                      \
      *(s8v*)((bB_) + woff[i_]) = bset[i_]; } }
#define PCOMP(bA_, bB_)                                                      \
  { _Pragma("unroll") for (int h_ = 0; h_ < 2; ++h_) {                       \
      s8v af_[4], bf_[4];                                                    \
      _Pragma("unroll") for (int q_ = 0; q_ < 4; ++q_) {                     \
        af_[q_] = *(const s8v*)((bA_) + afoff[h_][q_]);                      \
        bf_[q_] = *(const s8v*)((bB_) + bfoff[h_][q_]); }                    \
      _Pragma("unroll") for (int nj_ = 0; nj_ < 4; ++nj_)                    \
        _Pragma("unroll") for (int mq_ = 0; mq_ < 4; ++mq_)                  \
          acc[mq_][nj_] = __builtin_amdgcn_mfma_f32_16x16x32_bf16(           \
              af_[mq_], bf_[nj_], acc[mq_][nj_], 0, 0, 0); } }

  PLOADA(0); PLOADB(0);
  PWR(lds, lds + 32768);
  __syncthreads();
  for (int s = 0; s < 20; ++s) {
    char* cA = lds + (s & 1) * 16384;
    char* cB = lds + 32768 + (s & 1) * 16384;
    char* nA = lds + ((s + 1) & 1) * 16384;
    char* nB = lds + 32768 + ((s + 1) & 1) * 16384;
    if (s + 1 < 20) { PLOADA((s + 1) * 64); PLOADB((s + 1) * 64); }
    PCOMP(cA, cB);
    if (s + 1 < 20) { PWR(nA, nB); }
    __syncthreads();
  }
#pragma unroll
  for (int nj = 0; nj < 4; ++nj) {
    int n = n0 + 64 * wn + 16 * nj + r15;
    float bn = bias[n];
#pragma unroll
    for (int mq = 0; mq < 4; ++mq) {
      int m = r0 + 64 * wm + 16 * mq + 4 * g;
#pragma unroll
      for (int r = 0; r < 4; ++r)
        nproj[(size_t)(m + r) * D_SZ + n] = acc[mq][nj][r] + bn;
    }
  }
#undef PLOADA
#undef PLOADB
#undef PWR
#undef PCOMP
}

// ---------------- kernel 5: attention + logits + per-query loss partial -----
__global__ __launch_bounds__(256) void k_attn(
    const float* __restrict__ model, const float* __restrict__ proj,
    const int* __restrict__ topk, const int* __restrict__ labels,
    const float* __restrict__ clfW, const float* __restrict__ clfb,
    float* __restrict__ out, float* __restrict__ lossp) {
  __shared__ float P[8 * 512];
  __shared__ float red[4];
  int b = blockIdx.x, t = threadIdx.x;
  const float* src = proj + (size_t)b * 8 * 512;
#pragma unroll
  for (int i = 0; i < 4; ++i) {
    int o = i * 1024 + t * 4;
    *(float4*)&P[o] = *(const float4*)&src[o];
  }
  __syncthreads();
  float m0 = model[b * 512 + t], m1 = model[b * 512 + 256 + t];

  float sc[8];
#pragma unroll
  for (int k = 0; k < 8; ++k) {
    float p = m0 * P[k * 512 + t] + m1 * P[k * 512 + 256 + t];
#pragma unroll
    for (int o = 32; o > 0; o >>= 1) p += __shfl_down(p, o, 64);
    if ((t & 63) == 0) red[t >> 6] = p;
    __syncthreads();
    sc[k] = red[0] + red[1] + red[2] + red[3];
    __syncthreads();
  }
  const float scale = 0.04419417382415922f;  // 1/sqrt(512)
  float mx = -1e30f;
  float s_[8];
#pragma unroll
  for (int k = 0; k < 8; ++k) { s_[k] = sc[k] * scale; mx = fmaxf(mx, s_[k]); }
  float den = 0.f, att[8];
#pragma unroll
  for (int k = 0; k < 8; ++k) { att[k] = expf(s_[k] - mx); den += att[k]; }
  float iden = 1.0f / den;
#pragma unroll
  for (int k = 0; k < 8; ++k) att[k] *= iden;

  float z0 = 0.f, z1 = 0.f;
#pragma unroll
  for (int k = 0; k < 8; ++k) {
    z0 = fmaf(att[k], P[k * 512 + t], z0);
    z1 = fmaf(att[k], P[k * 512 + 256 + t], z1);
  }
#pragma unroll
  for (int c = 0; c < 2; ++c) {
    float lp = m0 * clfW[t * 2 + c] + m1 * clfW[(t + 256) * 2 + c] +
               z0 * clfW[(512 + t) * 2 + c] + z1 * clfW[(768 + t) * 2 + c];
#pragma unroll
    for (int o = 32; o > 0; o >>= 1) lp += __shfl_down(lp, o, 64);
    if ((t & 63) == 0) red[t >> 6] = lp;
    __syncthreads();
    if (t == 0) out[b * 2 + c] = red[0] + red[1] + red[2] + red[3] + clfb[c];
    __syncthreads();
  }
  float cp = 0.f, cn = 0.f;
  float p0 = 0.f, p1 = 0.f, n0 = 0.f, n1 = 0.f;
#pragma unroll
  for (int k = 0; k < 8; ++k) {
    int lb = labels[topk[b * 8 + k]];
    float mp = (lb == 1) ? 1.f : 0.f;
    float mn = (lb == 0) ? 1.f : 0.f;
    cp += mp; cn += mn;
    p0 = fmaf(mp, P[k * 512 + t], p0);
    p1 = fmaf(mp, P[k * 512 + 256 + t], p1);
    n0 = fmaf(mn, P[k * 512 + t], n0);
    n1 = fmaf(mn, P[k * 512 + 256 + t], n1);
  }
  float icp = 1.0f / (cp + 1e-6f), icn = 1.0f / (cn + 1e-6f);
  p0 *= icp; p1 *= icp; n0 *= icn; n1 *= icn;
  float lq = (m0 - p0) * (m0 - p0) + (m1 - p1) * (m1 - p1) -
             0.5f * ((m0 - n0) * (m0 - n0) + (m1 - n1) * (m1 - n1));
#pragma unroll
  for (int o = 32; o > 0; o >>= 1) lq += __shfl_down(lq, o, 64);
  if ((t & 63) == 0) red[t >> 6] = lq;
  __syncthreads();
  if (t == 0) lossp[b] = red[0] + red[1] + red[2] + red[3];
}

// ---------------- kernel 6: final loss reduction ----------------
__global__ __launch_bounds__(256) void k_loss(const float* __restrict__ lossp,
                                              float* __restrict__ out) {
  __shared__ float red[4];
  int t = threadIdx.x;
  float v = lossp[t];
#pragma unroll
  for (int o = 32; o > 0; o >>= 1) v += __shfl_down(v, o, 64);
  if ((t & 63) == 0) red[t >> 6] = v;
  __syncthreads();
  if (t == 0)
    out[512] = (red[0] + red[1] + red[2] + red[3]) * (1.0f / (256.0f * 512.0f));
}

extern "C" void kernel_launch(void* const* d_in, const int* in_sizes, int n_in,
                              void* d_out, int out_size, void* d_ws,
                              size_t ws_size, hipStream_t stream) {
  (void)in_sizes; (void)n_in; (void)out_size; (void)ws_size;
  const float* q      = (const float*)d_in[0];  // [256,1280]
  const float* model  = (const float*)d_in[1];  // [256,512]
  const float* emb    = (const float*)d_in[2];  // [100000,1280]
  const int*   labels = (const int*)d_in[3];    // [100000]
  const int*   excl   = (const int*)d_in[4];    // [256]
  const float* projW  = (const float*)d_in[5];  // [1280,512]
  const float* projb  = (const float*)d_in[6];  // [512]
  const float* clfW   = (const float*)d_in[7];  // [1024,2]
  const float* clfb   = (const float*)d_in[8];  // [2]
  float* out = (float*)d_out;                   // 512 logits + 1 loss

  // workspace layout (bytes)
  char* ws = (char*)d_ws;
  unsigned short* qn  = (unsigned short*)ws;                   // 655,360
  unsigned short* Wt  = (unsigned short*)(ws + 655360);        // 1,310,720
  unsigned short* ebf = (unsigned short*)(ws + 1966080);       // 256,000,000
  float* cvalv = (float*)(ws + 257966080);                     // 6,406,144
  int*   cvali = (int*)(ws + 264372224);                       // 6,406,144
  int*   topk  = (int*)(ws + 270778368);                       // 8,192
  float* nproj = (float*)(ws + 270786560);                     // 4,194,304
  float* lossp = (float*)(ws + 274980864);                     // 1,024

  k_prep<<<416, 256, 0, stream>>>(q, qn, projW, Wt);
  k_conv<<<2048, 256, 0, stream>>>(emb, ebf);
  k_sims_topk<<<1564, 256, 0, stream>>>(qn, ebf, excl, cvalv, cvali);
  k_merge<<<256, 256, 0, stream>>>(cvalv, cvali, topk);
  k_proj<<<dim3(16, 4), 256, 0, stream>>>(emb, topk, Wt, projb, nproj);
  k_attn<<<256, 256, 0, stream>>>(model, nproj, topk, labels, clfW, clfb, out, lossp);
  k_loss<<<1, 256, 0, stream>>>(lossp, out);
}

// Round 11
// 464.952 us; speedup vs baseline: 1.2280x; 1.0790x over previous
//
#include <hip/hip_runtime.h>
#include <hip/hip_bf16.h>
#include <math.h>

// Problem constants
#define B_SZ 256
#define N_SZ 100000
#define E_SZ 1280
#define D_SZ 512

#define NCH 1563   // ceil(100000 / 64) j-chunks

typedef __attribute__((ext_vector_type(8))) short s8v;   // 8 bf16
typedef __attribute__((ext_vector_type(4))) float f32x4; // MFMA acc

__device__ __forceinline__ unsigned short f2bf(float f) {
  unsigned int u = __float_as_uint(f);
  u += 0x7fffu + ((u >> 16) & 1u);   // RNE
  return (unsigned short)(u >> 16);
}
// packs 2 f32 -> bf16x2 (RNE); compiler emits v_cvt_pk_bf16_f32
__device__ __forceinline__ unsigned int pack2(float a, float b) {
  union { __hip_bfloat162 h; unsigned u; } c;
  c.h = __float22bfloat162_rn(make_float2(a, b));
  return c.u;
}
// async global->LDS, 16B per lane; LDS dest = wave-uniform base + lane*16
__device__ __forceinline__ void gload16(const void* g, void* l) {
  __builtin_amdgcn_global_load_lds(
      (const __attribute__((address_space(1))) void*)g,
      (__attribute__((address_space(3))) void*)l, 16, 0, 0);
}

// top-8 streaming update; requires locals: bv[8], bi[8], minv, mins
#define TOP8_UPDATE(v_, i_)                                                 \
  if ((v_) > minv) {                                                        \
    _Pragma("unroll")                                                       \
    for (int s_ = 0; s_ < 8; ++s_)                                          \
      if (s_ == mins) { bv[s_] = (v_); bi[s_] = (i_); }                     \
    minv = bv[0]; mins = 0;                                                 \
    _Pragma("unroll")                                                       \
    for (int s_ = 1; s_ < 8; ++s_)                                          \
      if (bv[s_] < minv) { minv = bv[s_]; mins = s_; }                      \
  }

// ---------------- kernel 0: stream-convert emb f32 -> bf16 ----------------
__global__ __launch_bounds__(256) void k_conv(const float* __restrict__ in,
                                              unsigned short* __restrict__ outp) {
  const size_t T = (size_t)gridDim.x * 256;
  const size_t total = 16000000u;  // (100000*1280)/8
  for (size_t i = (size_t)blockIdx.x * 256 + threadIdx.x; i < total; i += T) {
    const float4* p = ((const float4*)in) + 2 * i;
    float4 a = p[0], b = p[1];
    uint4 o;
    o.x = pack2(a.x, a.y); o.y = pack2(a.z, a.w);
    o.z = pack2(b.x, b.y); o.w = pack2(b.z, b.w);
    ((uint4*)outp)[i] = o;
  }
}

// ---------------- kernel 1: fused (normq | wt) prep ----------------
__global__ __launch_bounds__(256) void k_prep(const float* __restrict__ q,
                                              unsigned short* __restrict__ qn,
                                              const float* __restrict__ W,
                                              unsigned short* __restrict__ Wt) {
  __shared__ __align__(16) char sm[64 * 65 * 4];
  const int t = threadIdx.x;
  if (blockIdx.x < 256) {
    float* red = (float*)sm;
    int row = blockIdx.x;
    const float* src = q + (size_t)row * E_SZ;
    float x[5];
    float ss = 0.f;
#pragma unroll
    for (int i = 0; i < 5; ++i) { x[i] = src[t + 256 * i]; ss += x[i] * x[i]; }
#pragma unroll
    for (int o = 32; o > 0; o >>= 1) ss += __shfl_down(ss, o, 64);
    if ((t & 63) == 0) red[t >> 6] = ss;
    __syncthreads();
    float nrm = sqrtf(red[0] + red[1] + red[2] + red[3]);
    nrm = fmaxf(nrm, 1e-12f);
    float inv = 1.0f / nrm;
    unsigned short* dst = qn + (size_t)row * E_SZ;
#pragma unroll
    for (int i = 0; i < 5; ++i) dst[t + 256 * i] = f2bf(x[i] * inv);
  } else {
    float (*T)[65] = (float(*)[65])sm;
    int idx = blockIdx.x - 256;        // 0..159
    int kb = (idx % 20) * 64;
    int nb = (idx / 20) * 64;
#pragma unroll
    for (int i = 0; i < 16; ++i) {
      int kr = i * 4 + (t >> 6);
      T[kr][t & 63] = W[(size_t)(kb + kr) * D_SZ + nb + (t & 63)];
    }
    __syncthreads();
    const int n = t >> 2, ks = (t & 3) * 16;
    unsigned int ow[8];
#pragma unroll
    for (int j = 0; j < 8; ++j)
      ow[j] = (unsigned)f2bf(T[ks + 2 * j][n]) |
              ((unsigned)f2bf(T[ks + 2 * j + 1][n]) << 16);
    unsigned short* dst = Wt + (size_t)(nb + n) * E_SZ + kb + ks;
    *(uint4*)dst = make_uint4(ow[0], ow[1], ow[2], ow[3]);
    *(uint4*)(dst + 8) = make_uint4(ow[4], ow[5], ow[6], ow[7]);
  }
}

// ---------------- kernel 2: bf16 MFMA sims + fused per-chunk top-8 ----------
// 1563 blocks x 256 thr (4 waves). Tile 256q x 64j, K=1280 in 40 steps of 32.
// TRIPLE-buffered LDS, both operands via global_load_lds (zero staging VGPRs).
// Body(s): [vmcnt(5); barrier][compute s][lgkmcnt(0); barrier][stage s+2].
// Counted vmcnt(5) — never drains to 0 in the main loop: each wave keeps
// 5-10 gload_lds (5-10 KB) in flight continuously; 8 waves/CU => 40-80 KB/CU.
__global__ __launch_bounds__(256) void k_sims_topk(
    const unsigned short* __restrict__ qn, const unsigned short* __restrict__ ebf,
    const int* __restrict__ excl, float* __restrict__ cval) {
  __shared__ __align__(16) char lds[61440];
  // A bufs @0/16384/32768 (16KB each); B bufs @49152/53248/57344 (4KB each)
  const int t = threadIdx.x;
  const int l = t & 63, w = t >> 6;
  const int r15 = l & 15, g = l >> 4;
  const int jbase = blockIdx.x * 64;
  const int myq = (w << 6) + l;
  const int ex = excl[myq];

  f32x4 acc[4][4];
#pragma unroll
  for (int i = 0; i < 4; ++i)
#pragma unroll
    for (int j = 0; j < 4; ++j) acc[i][j] = (f32x4)0.f;

  // fragment read offsets (relative to buffer base): row*64 + g*16
  int afoff[4], bfoff[4];
#pragma unroll
  for (int mq = 0; mq < 4; ++mq)
    afoff[mq] = ((w << 6) + 16 * mq + r15) * 64 + g * 16;
#pragma unroll
  for (int nj = 0; nj < 4; ++nj)
    bfoff[nj] = (16 * nj + r15) * 64 + g * 16;

  // staging sources: A chunk c = i*256 + t -> row i*64 + (t>>2), kchunk t&3
  const int srow = t >> 2, skc = (t & 3) * 8;
  const unsigned short* aS0 = qn + (size_t)(srow) * E_SZ + skc;
  const unsigned short* aS1 = qn + (size_t)(64 + srow) * E_SZ + skc;
  const unsigned short* aS2 = qn + (size_t)(128 + srow) * E_SZ + skc;
  const unsigned short* aS3 = qn + (size_t)(192 + srow) * E_SZ + skc;
  const unsigned short* bS =
      ebf + (size_t)min(jbase + srow, N_SZ - 1) * E_SZ + skc;
  const int adst = t * 16;

#define STAGE(kt_, ab_, bb_)                                                 \
  { gload16(aS0 + (kt_), lds + (ab_) + adst);                                \
    gload16(aS1 + (kt_), lds + (ab_) + 4096 + adst);                         \
    gload16(aS2 + (kt_), lds + (ab_) + 8192 + adst);                         \
    gload16(aS3 + (kt_), lds + (ab_) + 12288 + adst);                        \
    gload16(bS + (kt_), lds + (bb_) + adst); }

  // prologue: stage steps 0 and 1 (10 gloads in flight)
  STAGE(0, 0, 49152);
  STAGE(32, 16384, 53248);

  int ab0 = 0, ab1 = 16384, ab2 = 32768;
  int bb0 = 49152, bb1 = 53248, bb2 = 57344;

  for (int s = 0; s < 40; ++s) {
    if (s < 39) {
      asm volatile("s_waitcnt vmcnt(5)" ::: "memory");
    } else {
      asm volatile("s_waitcnt vmcnt(0)" ::: "memory");
    }
    __builtin_amdgcn_s_barrier();
    // compute step s from (ab0, bb0)
    {
      s8v af[4], bf[4];
#pragma unroll
      for (int mq = 0; mq < 4; ++mq)
        af[mq] = *(const s8v*)(lds + ab0 + afoff[mq]);
#pragma unroll
      for (int nj = 0; nj < 4; ++nj)
        bf[nj] = *(const s8v*)(lds + bb0 + bfoff[nj]);
#pragma unroll
      for (int nj = 0; nj < 4; ++nj)
#pragma unroll
        for (int mq = 0; mq < 4; ++mq)
          acc[mq][nj] = __builtin_amdgcn_mfma_f32_16x16x32_bf16(
              af[mq], bf[nj], acc[mq][nj], 0, 0, 0);
    }
    asm volatile("s_waitcnt lgkmcnt(0)" ::: "memory");
    __builtin_amdgcn_s_barrier();
    if (s + 2 < 40) STAGE((s + 2) * 32, ab2, bb2);
    // rotate buffers
    int ta = ab0; ab0 = ab1; ab1 = ab2; ab2 = ta;
    int tb = bb0; bb0 = bb1; bb1 = bb2; bb2 = tb;
  }
#undef STAGE

  // ---- wave-local top-8 scan, 2 phases (waves {0,1} then {2,3}) ----
  for (int ph = 0; ph < 2; ++ph) {
    if ((w >> 1) == ph) {
      float* Sbuf = (float*)(lds + (w & 1) * 16640);  // 64 x 65 f32
#pragma unroll
      for (int mq = 0; mq < 4; ++mq)
#pragma unroll
        for (int nj = 0; nj < 4; ++nj)
#pragma unroll
          for (int r = 0; r < 4; ++r)
            Sbuf[(16 * mq + 4 * g + r) * 65 + 16 * nj + r15] = acc[mq][nj][r];
      float bv[8]; int bi[8];
#pragma unroll
      for (int s = 0; s < 8; ++s) { bv[s] = -1e30f; bi[s] = 0; }
      float minv = -1e30f; int mins = 0;
      const float* Srow = Sbuf + l * 65;
      for (int c = 0; c < 64; ++c) {
        int gj = jbase + c;
        float v = Srow[c];
        if (gj < N_SZ && gj != ex) { TOP8_UPDATE(v, gj); }
      }
      float* vdst = cval + (size_t)blockIdx.x * 4096 + myq * 8;
      *(float4*)vdst = make_float4(bv[0], bv[1], bv[2], bv[3]);
      *(float4*)(vdst + 4) = make_float4(bv[4], bv[5], bv[6], bv[7]);
      int* idst = (int*)(cval + (size_t)blockIdx.x * 4096 + 2048) + myq * 8;
      *(int4*)idst = make_int4(bi[0], bi[1], bi[2], bi[3]);
      *(int4*)(idst + 4) = make_int4(bi[4], bi[5], bi[6], bi[7]);
    }
    __syncthreads();
  }
}

// ---------------- kernel 3: merge per-chunk candidates -> global top-8 ------
__global__ __launch_bounds__(256) void k_merge(const float* __restrict__ cval,
                                               int* __restrict__ topk) {
  __shared__ float sv[2048];
  __shared__ int si[2048];
  const int q = blockIdx.x, t = threadIdx.x;
  float bv[8]; int bi[8];
#pragma unroll
  for (int s = 0; s < 8; ++s) { bv[s] = -1e30f; bi[s] = 0; }
  float minv = -1e30f; int mins = 0;
  for (int c = t; c < NCH; c += 256) {
    const float* vp = cval + (size_t)c * 4096 + q * 8;
    const int* ip = (const int*)(cval + (size_t)c * 4096 + 2048) + q * 8;
    float4 v0 = *(const float4*)vp, v1 = *(const float4*)(vp + 4);
    int4 i0 = *(const int4*)ip, i1 = *(const int4*)(ip + 4);
    float va[8] = {v0.x, v0.y, v0.z, v0.w, v1.x, v1.y, v1.z, v1.w};
    int ia[8] = {i0.x, i0.y, i0.z, i0.w, i1.x, i1.y, i1.z, i1.w};
#pragma unroll
    for (int s = 0; s < 8; ++s) {
      float v = va[s]; int ix = ia[s];
      TOP8_UPDATE(v, ix);
    }
  }
#pragma unroll
  for (int s = 0; s < 8; ++s) { sv[t * 8 + s] = bv[s]; si[t * 8 + s] = bi[s]; }
  __syncthreads();
  if (t < 64) {
    for (int rr = 1; rr < 4; ++rr) {
      int r = t + rr * 64;
#pragma unroll
      for (int s = 0; s < 8; ++s) {
        float v = sv[r * 8 + s]; int ix = si[r * 8 + s];
        TOP8_UPDATE(v, ix);
      }
    }
#pragma unroll
    for (int s = 0; s < 8; ++s) { sv[t * 8 + s] = bv[s]; si[t * 8 + s] = bi[s]; }
  }
  __syncthreads();
  if (t < 8) {
    for (int rr = 1; rr < 8; ++rr) {
      int r = t + rr * 8;
#pragma unroll
      for (int s = 0; s < 8; ++s) {
        float v = sv[r * 8 + s]; int ix = si[r * 8 + s];
        TOP8_UPDATE(v, ix);
      }
    }
#pragma unroll
    for (int s = 0; s < 8; ++s) { sv[t * 8 + s] = bv[s]; si[t * 8 + s] = bi[s]; }
  }
  __syncthreads();
  if (t == 0) {
    for (int r = 1; r < 8; ++r) {
#pragma unroll
      for (int s = 0; s < 8; ++s) {
        float v = sv[r * 8 + s]; int ix = si[r * 8 + s];
        TOP8_UPDATE(v, ix);
      }
    }
#pragma unroll
    for (int s = 0; s < 8; ++s) topk[q * 8 + s] = bi[s];
  }
}

// ---------------- kernel 4: gather + project via MFMA, bias fused -----------
// grid (16 Mtiles, 4 Ntiles), 256 thr (2x2 waves), tile 128x128, K=1280/64.
__global__ __launch_bounds__(256) void k_proj(
    const float* __restrict__ emb, const int* __restrict__ topk,
    const unsigned short* __restrict__ Wt, const float* __restrict__ bias,
    float* __restrict__ nproj) {
  __shared__ __align__(16) char lds[65536];  // A0 A1 B0 B1 each 16K
  const int t = threadIdx.x, l = t & 63, w = t >> 6;
  const int r15 = l & 15, g = l >> 4;
  const int wm = w >> 1, wn = w & 1;
  const int r0 = blockIdx.x * 128, n0 = blockIdx.y * 128;
  const int sr = t >> 3, kc = t & 7;

  int grow[4];
#pragma unroll
  for (int i = 0; i < 4; ++i) grow[i] = topk[r0 + i * 32 + sr];

  int woff[4];
#pragma unroll
  for (int i = 0; i < 4; ++i) {
    int row = i * 32 + sr;
    woff[i] = row * 128 + (((kc + (row & 7)) & 7) << 4);
  }
  int afoff[2][4], bfoff[2][4];
#pragma unroll
  for (int h = 0; h < 2; ++h) {
#pragma unroll
    for (int qq = 0; qq < 4; ++qq) {
      int rowa = 64 * wm + 16 * qq + r15;
      afoff[h][qq] = rowa * 128 + ((((h << 2) + g + (rowa & 7)) & 7) << 4);
      int rowb = 64 * wn + 16 * qq + r15;
      bfoff[h][qq] = rowb * 128 + ((((h << 2) + g + (rowb & 7)) & 7) << 4);
    }
  }

  f32x4 acc[4][4];
#pragma unroll
  for (int i = 0; i < 4; ++i)
#pragma unroll
    for (int j = 0; j < 4; ++j) acc[i][j] = (f32x4)0.f;

  float4 aset[4][2];
  s8v bset[4];

#define PLOADA(kt_)                                                          \
  { _Pragma("unroll") for (int i_ = 0; i_ < 4; ++i_) {                       \
      const float* s_ = emb + (size_t)grow[i_] * E_SZ + (kt_) + kc * 8;      \
      aset[i_][0] = *(const float4*)s_;                                      \
      aset[i_][1] = *(const float4*)(s_ + 4); } }
#define PLOADB(kt_)                                                          \
  { _Pragma("unroll") for (int i_ = 0; i_ < 4; ++i_)                         \
      bset[i_] = *(const s8v*)(Wt + (size_t)(n0 + i_ * 32 + sr) * E_SZ +     \
                               (kt_) + kc * 8); }
#define PWR(bA_, bB_)                                                        \
  { _Pragma("unroll") for (int i_ = 0; i_ < 4; ++i_) {                       \
      uint4 p_;                                                              \
      p_.x = pack2(aset[i_][0].x, aset[i_][0].y);                            \
      p_.y = pack2(aset[i_][0].z, aset[i_][0].w);                            \
      p_.z = pack2(aset[i_][1].x, aset[i_][1].y);                            \
      p_.w = pack2(aset[i_][1].z, aset[i_][1].w);                            \
      *(uint4*)((bA_) + woff[i_]) = p_;                                      \
      *(s8v*)((bB_) + woff[i_]) = bset[i_]; } }
#define PCOMP(bA_, bB_)                                                      \
  { _Pragma("unroll") for (int h_ = 0; h_ < 2; ++h_) {                       \
      s8v af_[4], bf_[4];                                                    \
      _Pragma("unroll") for (int q_ = 0; q_ < 4; ++q_) {                     \
        af_[q_] = *(const s8v*)((bA_) + afoff[h_][q_]);                      \
        bf_[q_] = *(const s8v*)((bB_) + bfoff[h_][q_]); }                    \
      _Pragma("unroll") for (int nj_ = 0; nj_ < 4; ++nj_)                    \
        _Pragma("unroll") for (int mq_ = 0; mq_ < 4; ++mq_)                  \
          acc[mq_][nj_] = __builtin_amdgcn_mfma_f32_16x16x32_bf16(           \
              af_[mq_], bf_[nj_], acc[mq_][nj_], 0, 0, 0); } }

  PLOADA(0); PLOADB(0);
  PWR(lds, lds + 32768);
  __syncthreads();
  for (int s = 0; s < 20; ++s) {
    char* cA = lds + (s & 1) * 16384;
    char* cB = lds + 32768 + (s & 1) * 16384;
    char* nA = lds + ((s + 1) & 1) * 16384;
    char* nB = lds + 32768 + ((s + 1) & 1) * 16384;
    if (s + 1 < 20) { PLOADA((s + 1) * 64); PLOADB((s + 1) * 64); }
    PCOMP(cA, cB);
    if (s + 1 < 20) { PWR(nA, nB); }
    __syncthreads();
  }
#pragma unroll
  for (int nj = 0; nj < 4; ++nj) {
    int n = n0 + 64 * wn + 16 * nj + r15;
    float bn = bias[n];
#pragma unroll
    for (int mq = 0; mq < 4; ++mq) {
      int m = r0 + 64 * wm + 16 * mq + 4 * g;
#pragma unroll
      for (int r = 0; r < 4; ++r)
        nproj[(size_t)(m + r) * D_SZ + n] = acc[mq][nj][r] + bn;
    }
  }
#undef PLOADA
#undef PLOADB
#undef PWR
#undef PCOMP
}

// ---------------- kernel 5: attention + logits + per-query loss partial -----
__global__ __launch_bounds__(256) void k_attn(
    const float* __restrict__ model, const float* __restrict__ proj,
    const int* __restrict__ topk, const int* __restrict__ labels,
    const float* __restrict__ clfW, const float* __restrict__ clfb,
    float* __restrict__ out, float* __restrict__ lossp) {
  __shared__ float P[8 * 512];
  __shared__ float red[4];
  int b = blockIdx.x, t = threadIdx.x;
  const float* src = proj + (size_t)b * 8 * 512;
#pragma unroll
  for (int i = 0; i < 4; ++i) {
    int o = i * 1024 + t * 4;
    *(float4*)&P[o] = *(const float4*)&src[o];
  }
  __syncthreads();
  float m0 = model[b * 512 + t], m1 = model[b * 512 + 256 + t];

  float sc[8];
#pragma unroll
  for (int k = 0; k < 8; ++k) {
    float p = m0 * P[k * 512 + t] + m1 * P[k * 512 + 256 + t];
#pragma unroll
    for (int o = 32; o > 0; o >>= 1) p += __shfl_down(p, o, 64);
    if ((t & 63) == 0) red[t >> 6] = p;
    __syncthreads();
    sc[k] = red[0] + red[1] + red[2] + red[3];
    __syncthreads();
  }
  const float scale = 0.04419417382415922f;  // 1/sqrt(512)
  float mx = -1e30f;
  float s_[8];
#pragma unroll
  for (int k = 0; k < 8; ++k) { s_[k] = sc[k] * scale; mx = fmaxf(mx, s_[k]); }
  float den = 0.f, att[8];
#pragma unroll
  for (int k = 0; k < 8; ++k) { att[k] = expf(s_[k] - mx); den += att[k]; }
  float iden = 1.0f / den;
#pragma unroll
  for (int k = 0; k < 8; ++k) att[k] *= iden;

  float z0 = 0.f, z1 = 0.f;
#pragma unroll
  for (int k = 0; k < 8; ++k) {
    z0 = fmaf(att[k], P[k * 512 + t], z0);
    z1 = fmaf(att[k], P[k * 512 + 256 + t], z1);
  }
#pragma unroll
  for (int c = 0; c < 2; ++c) {
    float lp = m0 * clfW[t * 2 + c] + m1 * clfW[(t + 256) * 2 + c] +
               z0 * clfW[(512 + t) * 2 + c] + z1 * clfW[(768 + t) * 2 + c];
#pragma unroll
    for (int o = 32; o > 0; o >>= 1) lp += __shfl_down(lp, o, 64);
    if ((t & 63) == 0) red[t >> 6] = lp;
    __syncthreads();
    if (t == 0) out[b * 2 + c] = red[0] + red[1] + red[2] + red[3] + clfb[c];
    __syncthreads();
  }
  float cp = 0.f, cn = 0.f;
  float p0 = 0.f, p1 = 0.f, n0 = 0.f, n1 = 0.f;
#pragma unroll
  for (int k = 0; k < 8; ++k) {
    int lb = labels[topk[b * 8 + k]];
    float mp = (lb == 1) ? 1.f : 0.f;
    float mn = (lb == 0) ? 1.f : 0.f;
    cp += mp; cn += mn;
    p0 = fmaf(mp, P[k * 512 + t], p0);
    p1 = fmaf(mp, P[k * 512 + 256 + t], p1);
    n0 = fmaf(mn, P[k * 512 + t], n0);
    n1 = fmaf(mn, P[k * 512 + 256 + t], n1);
  }
  float icp = 1.0f / (cp + 1e-6f), icn = 1.0f / (cn + 1e-6f);
  p0 *= icp; p1 *= icp; n0 *= icn; n1 *= icn;
  float lq = (m0 - p0) * (m0 - p0) + (m1 - p1) * (m1 - p1) -
             0.5f * ((m0 - n0) * (m0 - n0) + (m1 - n1) * (m1 - n1));
#pragma unroll
  for (int o = 32; o > 0; o >>= 1) lq += __shfl_down(lq, o, 64);
  if ((t & 63) == 0) red[t >> 6] = lq;
  __syncthreads();
  if (t == 0) lossp[b] = red[0] + red[1] + red[2] + red[3];
}

// ---------------- kernel 6: final loss reduction ----------------
__global__ __launch_bounds__(256) void k_loss(const float* __restrict__ lossp,
                                              float* __restrict__ out) {
  __shared__ float red[4];
  int t = threadIdx.x;
  float v = lossp[t];
#pragma unroll
  for (int o = 32; o > 0; o >>= 1) v += __shfl_down(v, o, 64);
  if ((t & 63) == 0) red[t >> 6] = v;
  __syncthreads();
  if (t == 0)
    out[512] = (red[0] + red[1] + red[2] + red[3]) * (1.0f / (256.0f * 512.0f));
}

extern "C" void kernel_launch(void* const* d_in, const int* in_sizes, int n_in,
                              void* d_out, int out_size, void* d_ws,
                              size_t ws_size, hipStream_t stream) {
  (void)in_sizes; (void)n_in; (void)out_size; (void)ws_size;
  const float* q      = (const float*)d_in[0];  // [256,1280]
  const float* model  = (const float*)d_in[1];  // [256,512]
  const float* emb    = (const float*)d_in[2];  // [100000,1280]
  const int*   labels = (const int*)d_in[3];    // [100000]
  const int*   excl   = (const int*)d_in[4];    // [256]
  const float* projW  = (const float*)d_in[5];  // [1280,512]
  const float* projb  = (const float*)d_in[6];  // [512]
  const float* clfW   = (const float*)d_in[7];  // [1024,2]
  const float* clfb   = (const float*)d_in[8];  // [2]
  float* out = (float*)d_out;                   // 512 logits + 1 loss

  // workspace layout (bytes)
  char* ws = (char*)d_ws;
  unsigned short* qn  = (unsigned short*)ws;                   // 655,360
  unsigned short* Wt  = (unsigned short*)(ws + 655360);        // 1,310,720
  unsigned short* ebf = (unsigned short*)(ws + 1966080);       // 256,000,000
  float* cval  = (float*)(ws + 257966080);                     // 25,608,192
  int*   topk  = (int*)(ws + 283574272);                       // 8,192
  float* nproj = (float*)(ws + 283582464);                     // 4,194,304
  float* lossp = (float*)(ws + 287776768);                     // 1,024

  k_prep<<<416, 256, 0, stream>>>(q, qn, projW, Wt);
  k_conv<<<2048, 256, 0, stream>>>(emb, ebf);
  k_sims_topk<<<NCH, 256, 0, stream>>>(qn, ebf, excl, cval);
  k_merge<<<256, 256, 0, stream>>>(cval, topk);
  k_proj<<<dim3(16, 4), 256, 0, stream>>>(emb, topk, Wt, projb, nproj);
  k_attn<<<256, 256, 0, stream>>>(model, nproj, topk, labels, clfW, clfb, out, lossp);
  k_loss<<<1, 256, 0, stream>>>(lossp, out);
}